// Round 7
// baseline (415.367 us; speedup 1.0000x reference)
//
#include <hip/hip_runtime.h>
#include <hip/hip_bf16.h>

// GAT fused masked attention, B=4 N=4096 D=128 fp32.
// Round 5 kernel, 3rd submit (broker timeouts; never ran): 8 waves (2
// q-halves x 4 key-quarters), 32x32x16 MFMA (2x FLOP per LDS byte vs 16x16),
// Q in regs, per-wave P in LDS, T3/T4 pipeline (counted vmcnt(4) + raw
// s_barrier + adj prefetch 1 tile ahead).
// Target: adj HBM stream (256 MB ~ 41 us) as critical path; LDS under it.
// Needs ws_size >= 8 MB.

#define NN 4096
#define DD 128
#define BK 128
#define NT (NN / BK)

#define XBT_REL 32768                    // xbt tile within a buffer
#define BUF1_OFF 65536
#define P_OFF 131072                     // 8 waves x [32 q][72 B]
#define P_WSTRIDE 2304
#define LDS_BYTES (P_OFF + 8 * P_WSTRIDE)   // 149504

typedef __attribute__((ext_vector_type(8))) short bf16x8;
typedef __attribute__((ext_vector_type(16))) float f32x16;

static __device__ __forceinline__ unsigned f2bf(float f) {
    union { float f; unsigned u; } v; v.f = f;
    return (v.u + 0x7fffu + ((v.u >> 16) & 1u)) >> 16;  // RNE
}

static __device__ __forceinline__ void gl_lds16(const void* g, void* l) {
    __builtin_amdgcn_global_load_lds(
        (const __attribute__((address_space(1))) unsigned*)g,
        (__attribute__((address_space(3))) unsigned*)l, 16, 0, 0);
}

// ---------------- prepass: X fp32 -> xb (bf16 [b][n][d]) + xbt (bf16 [b][d][n])
__global__ __launch_bounds__(256)
void gat_prep(const float* __restrict__ X, unsigned short* __restrict__ xb,
              unsigned short* __restrict__ xbt) {
    __shared__ unsigned short tile[64][132];
    const int t = threadIdx.x;
    const int b  = blockIdx.x >> 6;
    const int kc = blockIdx.x & 63;
    const float* src = X + ((size_t)b * NN + kc * 64) * DD;
    unsigned short* xbo = xb + ((size_t)b * NN + kc * 64) * DD;

    #pragma unroll
    for (int it = 0; it < 8; ++it) {
        int f = it * 256 + t;
        int k = f >> 5, d4 = (f & 31) * 4;
        float4 v = *(const float4*)(src + (size_t)f * 4);
        uint2 pk;
        pk.x = f2bf(v.x) | (f2bf(v.y) << 16);
        pk.y = f2bf(v.z) | (f2bf(v.w) << 16);
        *(uint2*)(xbo + (size_t)f * 4) = pk;
        *(uint2*)(&tile[k][d4]) = pk;
    }
    __syncthreads();
    const int d = t >> 1, kb0 = (t & 1) * 32;
    unsigned short* dst = xbt + (size_t)b * DD * NN + (size_t)d * NN + kc * 64 + kb0;
    #pragma unroll
    for (int c = 0; c < 4; ++c) {
        union { uint4 o; unsigned short e[8]; } u;
        #pragma unroll
        for (int j = 0; j < 8; ++j) u.e[j] = tile[kb0 + c * 8 + j][d];
        *(uint4*)(dst + c * 8) = u.o;
    }
}

// ---------------- main fused kernel: 512 thr = 8 waves (rw 2 x kh 4)
__global__ __launch_bounds__(512, 2)
void gat_fused(const unsigned short* __restrict__ xb,
               const unsigned short* __restrict__ xbt,
               const int* __restrict__ adj,
               float* __restrict__ out) {
    extern __shared__ char lds[];
    const int t = threadIdx.x;
    const int w = t >> 6, l = t & 63;
    const int l32 = l & 31, h5 = l >> 5;
    const int rw = w >> 2;         // 0..1: 32 q rows each
    const int kh = w & 3;          // 0..3: 32 keys each
    const int bid  = blockIdx.x;
    const int b    = bid >> 6;
    const int row0 = (bid & 63) * 64;
    const int qbase = row0 + rw * 32;
    const int kbase = kh * 32;

    const char* xb_b  = (const char*)(xb  + (size_t)b * NN * DD);
    const char* xbt_b = (const char*)(xbt + (size_t)b * DD * NN);
    const int*  Ag    = adj + (size_t)b * NN * NN;
    float*      Og    = out + (size_t)b * NN * DD;

    // Q as B-operand frags (row q = l32, k-chunks of 16): 8 x bf16x8 in regs
    bf16x8 qfrag[8];
    {
        const char* qp = xb_b + (size_t)(qbase + l32) * 256;
        #pragma unroll
        for (int c = 0; c < 8; ++c)
            qfrag[c] = *(const bf16x8*)(qp + c * 32 + h5 * 16);
    }

    // staging: 4 xb + 4 xbt gl_lds16 per wave; src XOR-swizzled, LDS linear
    int off_xb[4], off_xbt[4];
    #pragma unroll
    for (int j = 0; j < 4; ++j) {
        int r = w * 16 + 4 * j + (l >> 4);
        off_xb[j]  = r * 256      + (((l & 15) ^ (r & 7)) * 16);
        off_xbt[j] = r * (NN * 2) + (((l & 15) ^ (r & 7)) * 16);
    }
    char* bufA = lds;
    char* bufB = lds + BUF1_OFF;
    char* pw   = lds + P_OFF + w * P_WSTRIDE;
    const int* arow = Ag + (size_t)(qbase + l32) * NN + kbase + 4 * h5;

#define STAGE(BUF, KEY0) do {                                                  \
    _Pragma("unroll")                                                          \
    for (int j = 0; j < 4; ++j) {                                              \
        gl_lds16(xb_b  + (size_t)(KEY0) * 256 + off_xb[j],                     \
                 (BUF) + w * 4096 + j * 1024);                                 \
        gl_lds16(xbt_b + (size_t)(KEY0) * 2 + off_xbt[j],                      \
                 (BUF) + XBT_REL + w * 4096 + j * 1024);                       \
    }                                                                          \
} while (0)

    // prologue: stage tile 0, adj tile 0
    STAGE(bufA, 0);
    int4 avA[4];
    #pragma unroll
    for (int g = 0; g < 4; ++g) avA[g] = *(const int4*)(arow + g * 8);

    f32x16 oacc[4];
    #pragma unroll
    for (int d = 0; d < 4; ++d) oacc[d] = (f32x16)(0.0f);
    float psum = 0.f;

#define COMPUTE(BUF, AV) do {                                                  \
    f32x16 sacc = (f32x16)(0.0f);                                              \
    {                                                                          \
        const int krow = kbase + l32;                                          \
        const char* kp = (BUF) + krow * 256;                                   \
        const int sw = krow & 7;                                               \
        _Pragma("unroll")                                                      \
        for (int c = 0; c < 8; ++c) {                                          \
            bf16x8 kf = *(const bf16x8*)(kp + (((2 * c + h5) ^ sw) * 16));     \
            sacc = __builtin_amdgcn_mfma_f32_32x32x16_bf16(                    \
                kf, qfrag[c], sacc, 0, 0, 0);                                  \
        }                                                                      \
    }                                                                          \
    {                                                                          \
        const float SC = 0.08838834764831845f;  /* 1/sqrt(128) */              \
        _Pragma("unroll")                                                      \
        for (int g = 0; g < 4; ++g) {                                          \
            int4 a = (AV)[g];                                                  \
            float p0 = (a.x > 0) ? __expf(sacc[4 * g + 0] * SC) : 0.f;         \
            float p1 = (a.y > 0) ? __expf(sacc[4 * g + 1] * SC) : 0.f;         \
            float p2 = (a.z > 0) ? __expf(sacc[4 * g + 2] * SC) : 0.f;         \
            float p3 = (a.w > 0) ? __expf(sacc[4 * g + 3] * SC) : 0.f;         \
            psum += p0 + p1 + p2 + p3;                                         \
            uint2 pk;                                                          \
            pk.x = f2bf(p0) | (f2bf(p1) << 16);                                \
            pk.y = f2bf(p2) | (f2bf(p3) << 16);                                \
            *(uint2*)(pw + l32 * 72 + g * 16 + h5 * 8) = pk;                   \
        }                                                                      \
    }                                                                          \
    {                                                                          \
        bf16x8 pf0 = *(const bf16x8*)(pw + l32 * 72 + h5 * 16);                \
        bf16x8 pf1 = *(const bf16x8*)(pw + l32 * 72 + 32 + h5 * 16);           \
        _Pragma("unroll")                                                      \
        for (int db = 0; db < 4; ++db) {                                       \
            const int vrow = db * 32 + l32;                                    \
            const int swv = vrow & 7;                                          \
            const char* vp = (BUF) + XBT_REL + vrow * 256;                     \
            bf16x8 v0 = *(const bf16x8*)(vp + (((4 * kh + h5) ^ swv) * 16));   \
            oacc[db] = __builtin_amdgcn_mfma_f32_32x32x16_bf16(                \
                pf0, v0, oacc[db], 0, 0, 0);                                   \
            bf16x8 v1 = *(const bf16x8*)(vp + (((4 * kh + 2 + h5) ^ swv) * 16)); \
            oacc[db] = __builtin_amdgcn_mfma_f32_32x32x16_bf16(                \
                pf1, v1, oacc[db], 0, 0, 0);                                   \
        }                                                                      \
    }                                                                          \
} while (0)

    // ---- pipelined main loop: one barrier per tile, counted vmcnt ----
    for (int kt = 0; kt < NT - 1; ++kt) {
        int4 avB[4];
        #pragma unroll
        for (int g = 0; g < 4; ++g)
            avB[g] = *(const int4*)(arow + (kt + 1) * BK + g * 8);
        // own stage(kt) + adj(kt) drained; only the 4 avB loads may remain
        asm volatile("s_waitcnt vmcnt(4)" ::: "memory");
        __builtin_amdgcn_s_barrier();
        STAGE(bufB, (kt + 1) * BK);       // flies under COMPUTE(kt)
        COMPUTE(bufA, avA);
        char* tmp = bufA; bufA = bufB; bufB = tmp;
        #pragma unroll
        for (int g = 0; g < 4; ++g) avA[g] = avB[g];
    }
    asm volatile("s_waitcnt vmcnt(0)" ::: "memory");
    __builtin_amdgcn_s_barrier();
    COMPUTE(bufA, avA);

    // ---------------- epilogue: combine 4 key-quarters, normalize, store
    psum += __shfl_xor(psum, 32, 64);      // fold h5 halves (same q)
    __syncthreads();                        // all tiles done; repurpose LDS

    // slot w: [32 q][136 f32 stride] partial O; psarea after slots
    float* slot = (float*)(lds + w * 17408);
    #pragma unroll
    for (int db = 0; db < 4; ++db)
        #pragma unroll
        for (int r = 0; r < 16; ++r) {
            const int lrow = (r & 3) + 8 * (r >> 2) + 4 * h5;
            slot[lrow * 136 + db * 32 + l32] = oacc[db][r];
        }
    float* psarea = (float*)(lds + 139264);  // [8 waves][32 q]
    if (l < 32) psarea[w * 32 + l] = psum;
    __syncthreads();

    {
        const int R   = w * 8 + (l >> 3);    // block-local out row 0..63
        const int q32 = R & 31, rwR = R >> 5;
        const int d0  = (l & 7) * 16;
        float tot = psarea[(rwR * 4 + 0) * 32 + q32]
                  + psarea[(rwR * 4 + 1) * 32 + q32]
                  + psarea[(rwR * 4 + 2) * 32 + q32]
                  + psarea[(rwR * 4 + 3) * 32 + q32];
        float invt = 1.0f / tot;
        float4 acc[4];
        #pragma unroll
        for (int j = 0; j < 4; ++j) acc[j] = (float4){0.f, 0.f, 0.f, 0.f};
        #pragma unroll
        for (int kx = 0; kx < 4; ++kx) {
            const float* sp = (const float*)(lds + (rwR * 4 + kx) * 17408)
                              + q32 * 136 + d0;
            #pragma unroll
            for (int j = 0; j < 4; ++j) {
                float4 v = *(const float4*)(sp + 4 * j);
                acc[j].x += v.x; acc[j].y += v.y;
                acc[j].z += v.z; acc[j].w += v.w;
            }
        }
        float* op = Og + (size_t)(row0 + R) * DD + d0;
        #pragma unroll
        for (int j = 0; j < 4; ++j) {
            float4 res;
            res.x = acc[j].x * invt; res.y = acc[j].y * invt;
            res.z = acc[j].z * invt; res.w = acc[j].w * invt;
            *(float4*)(op + 4 * j) = res;
        }
    }
#undef COMPUTE
#undef STAGE
}

extern "C" void kernel_launch(void* const* d_in, const int* in_sizes, int n_in,
                              void* d_out, int out_size, void* d_ws, size_t ws_size,
                              hipStream_t stream) {
    const float* X   = (const float*)d_in[0];
    const int*   adj = (const int*)d_in[1];
    float*       out = (float*)d_out;
    unsigned short* xb  = (unsigned short*)d_ws;              // 4 MB bf16 X
    unsigned short* xbt = xb + (size_t)4 * NN * DD;           // 4 MB bf16 X^T

    hipFuncSetAttribute((const void*)gat_fused,
                        hipFuncAttributeMaxDynamicSharedMemorySize, LDS_BYTES);
    gat_prep<<<dim3(256), dim3(256), 0, stream>>>(X, xb, xbt);
    gat_fused<<<dim3(256), dim3(512), LDS_BYTES, stream>>>(xb, xbt, adj, out);
}

// Round 8
// 395.152 us; speedup vs baseline: 1.0512x; 1.0512x over previous
//
#include <hip/hip_runtime.h>
#include <hip/hip_bf16.h>

// GAT fused masked attention, B=4 N=4096 D=128 fp32.
// Round 8: round-5 structure (8 waves, 32x32x16 MFMA, T3/T4 pipeline) plus:
//  - T12 in-register P: cvt_pk_bf16 + permlane32_swap assemble PV A-frags
//    directly from QK^T accumulators (no P LDS roundtrip, no lgkm dep).
//  - adj prefetched 2 tiles ahead (avA/avB/avC), vmcnt(4) ledger unchanged.
// Needs ws_size >= 8 MB.

#define NN 4096
#define DD 128
#define BK 128
#define NT (NN / BK)

#define XBT_REL 32768                    // xbt tile within a buffer
#define BUF1_OFF 65536
#define PS_OFF 139264                    // psarea after epilogue slots
#define LDS_BYTES (PS_OFF + 1024)        // 140288

typedef __attribute__((ext_vector_type(8))) short bf16x8;
typedef __attribute__((ext_vector_type(16))) float f32x16;

static __device__ __forceinline__ unsigned f2bf(float f) {
    union { float f; unsigned u; } v; v.f = f;
    return (v.u + 0x7fffu + ((v.u >> 16) & 1u)) >> 16;  // RNE
}

static __device__ __forceinline__ void gl_lds16(const void* g, void* l) {
    __builtin_amdgcn_global_load_lds(
        (const __attribute__((address_space(1))) unsigned*)g,
        (__attribute__((address_space(3))) unsigned*)l, 16, 0, 0);
}

static __device__ __forceinline__ unsigned cvtpk(float lo, float hi) {
    unsigned r;
    asm("v_cvt_pk_bf16_f32 %0, %1, %2" : "=v"(r) : "v"(lo), "v"(hi));
    return r;
}
// swap: a' = (a_lo, b_lo), b' = (a_hi, b_hi) across the lane<32 / lane>=32 halves
static __device__ __forceinline__ void plswap(unsigned& a, unsigned& b) {
    asm volatile("v_permlane32_swap_b32 %0, %1" : "+v"(a), "+v"(b));
}

// ---------------- prepass: X fp32 -> xb (bf16 [b][n][d]) + xbt (bf16 [b][d][n])
__global__ __launch_bounds__(256)
void gat_prep(const float* __restrict__ X, unsigned short* __restrict__ xb,
              unsigned short* __restrict__ xbt) {
    __shared__ unsigned short tile[64][132];
    const int t = threadIdx.x;
    const int b  = blockIdx.x >> 6;
    const int kc = blockIdx.x & 63;
    const float* src = X + ((size_t)b * NN + kc * 64) * DD;
    unsigned short* xbo = xb + ((size_t)b * NN + kc * 64) * DD;

    #pragma unroll
    for (int it = 0; it < 8; ++it) {
        int f = it * 256 + t;
        int k = f >> 5, d4 = (f & 31) * 4;
        float4 v = *(const float4*)(src + (size_t)f * 4);
        uint2 pk;
        pk.x = f2bf(v.x) | (f2bf(v.y) << 16);
        pk.y = f2bf(v.z) | (f2bf(v.w) << 16);
        *(uint2*)(xbo + (size_t)f * 4) = pk;
        *(uint2*)(&tile[k][d4]) = pk;
    }
    __syncthreads();
    const int d = t >> 1, kb0 = (t & 1) * 32;
    unsigned short* dst = xbt + (size_t)b * DD * NN + (size_t)d * NN + kc * 64 + kb0;
    #pragma unroll
    for (int c = 0; c < 4; ++c) {
        union { uint4 o; unsigned short e[8]; } u;
        #pragma unroll
        for (int j = 0; j < 8; ++j) u.e[j] = tile[kb0 + c * 8 + j][d];
        *(uint4*)(dst + c * 8) = u.o;
    }
}

// ---------------- main fused kernel: 512 thr = 8 waves (rw 2 x kh 4)
__global__ __launch_bounds__(512, 2)
void gat_fused(const unsigned short* __restrict__ xb,
               const unsigned short* __restrict__ xbt,
               const int* __restrict__ adj,
               float* __restrict__ out) {
    extern __shared__ char lds[];
    const int t = threadIdx.x;
    const int w = t >> 6, l = t & 63;
    const int l32 = l & 31, h5 = l >> 5;
    const int rw = w >> 2;         // 0..1: 32 q rows each
    const int kh = w & 3;          // 0..3: 32 keys each
    const int bid  = blockIdx.x;
    const int b    = bid >> 6;
    const int row0 = (bid & 63) * 64;
    const int qbase = row0 + rw * 32;
    const int kbase = kh * 32;

    const char* xb_b  = (const char*)(xb  + (size_t)b * NN * DD);
    const char* xbt_b = (const char*)(xbt + (size_t)b * DD * NN);
    const int*  Ag    = adj + (size_t)b * NN * NN;
    float*      Og    = out + (size_t)b * NN * DD;

    // Q as B-operand frags (row q = l32, k-chunks of 16): 8 x bf16x8 in regs
    bf16x8 qfrag[8];
    {
        const char* qp = xb_b + (size_t)(qbase + l32) * 256;
        #pragma unroll
        for (int c = 0; c < 8; ++c)
            qfrag[c] = *(const bf16x8*)(qp + c * 32 + h5 * 16);
    }

    // staging: 4 xb + 4 xbt gl_lds16 per wave; src XOR-swizzled, LDS linear
    int off_xb[4], off_xbt[4];
    #pragma unroll
    for (int j = 0; j < 4; ++j) {
        int r = w * 16 + 4 * j + (l >> 4);
        off_xb[j]  = r * 256      + (((l & 15) ^ (r & 7)) * 16);
        off_xbt[j] = r * (NN * 2) + (((l & 15) ^ (r & 7)) * 16);
    }
    char* bufA = lds;
    char* bufB = lds + BUF1_OFF;
    const int* arow = Ag + (size_t)(qbase + l32) * NN + kbase + 4 * h5;

#define STAGE(BUF, KEY0) do {                                                  \
    _Pragma("unroll")                                                          \
    for (int j = 0; j < 4; ++j) {                                              \
        gl_lds16(xb_b  + (size_t)(KEY0) * 256 + off_xb[j],                     \
                 (BUF) + w * 4096 + j * 1024);                                 \
        gl_lds16(xbt_b + (size_t)(KEY0) * 2 + off_xbt[j],                      \
                 (BUF) + XBT_REL + w * 4096 + j * 1024);                       \
    }                                                                          \
} while (0)

    // prologue: stage tile 0; adj tiles 0 and 1
    STAGE(bufA, 0);
    int4 avA[4], avB[4], avC[4];
    #pragma unroll
    for (int g = 0; g < 4; ++g) avA[g] = *(const int4*)(arow + g * 8);
    #pragma unroll
    for (int g = 0; g < 4; ++g) avB[g] = *(const int4*)(arow + BK + g * 8);

    f32x16 oacc[4];
    #pragma unroll
    for (int d = 0; d < 4; ++d) oacc[d] = (f32x16)(0.0f);
    float psum = 0.f;

#define COMPUTE(BUF, AV) do {                                                  \
    f32x16 sacc = (f32x16)(0.0f);                                              \
    {                                                                          \
        const int krow = kbase + l32;                                          \
        const char* kp = (BUF) + krow * 256;                                   \
        const int sw = krow & 7;                                               \
        _Pragma("unroll")                                                      \
        for (int c = 0; c < 8; ++c) {                                          \
            bf16x8 kf = *(const bf16x8*)(kp + (((2 * c + h5) ^ sw) * 16));     \
            sacc = __builtin_amdgcn_mfma_f32_32x32x16_bf16(                    \
                kf, qfrag[c], sacc, 0, 0, 0);                                  \
        }                                                                      \
    }                                                                          \
    float p[16];                                                               \
    {                                                                          \
        const float SC = 0.08838834764831845f;  /* 1/sqrt(128) */              \
        _Pragma("unroll")                                                      \
        for (int g = 0; g < 4; ++g) {                                          \
            int4 a = (AV)[g];                                                  \
            p[4*g+0] = (a.x > 0) ? __expf(sacc[4*g+0] * SC) : 0.f;             \
            p[4*g+1] = (a.y > 0) ? __expf(sacc[4*g+1] * SC) : 0.f;             \
            p[4*g+2] = (a.z > 0) ? __expf(sacc[4*g+2] * SC) : 0.f;             \
            p[4*g+3] = (a.w > 0) ? __expf(sacc[4*g+3] * SC) : 0.f;             \
            psum += p[4*g+0] + p[4*g+1] + p[4*g+2] + p[4*g+3];                 \
        }                                                                      \
    }                                                                          \
    /* T12: assemble PV A-frags in-register (lane q=l32 holds 32 keys).    */  \
    /* key_local(r,h5) = (r&3)+8*(r>>2)+4*h5; chunk c needs keys c*16+8h5+j */  \
    union { bf16x8 v; unsigned u[4]; } pf0u, pf1u;                             \
    {                                                                          \
        unsigned a0 = cvtpk(p[0],  p[1]),  b0 = cvtpk(p[4],  p[5]);            \
        unsigned a1 = cvtpk(p[2],  p[3]),  b1 = cvtpk(p[6],  p[7]);            \
        plswap(a0, b0);  plswap(a1, b1);                                       \
        pf0u.u[0] = a0; pf0u.u[1] = a1; pf0u.u[2] = b0; pf0u.u[3] = b1;        \
        unsigned a2 = cvtpk(p[8],  p[9]),  b2 = cvtpk(p[12], p[13]);           \
        unsigned a3 = cvtpk(p[10], p[11]), b3 = cvtpk(p[14], p[15]);           \
        plswap(a2, b2);  plswap(a3, b3);                                       \
        pf1u.u[0] = a2; pf1u.u[1] = a3; pf1u.u[2] = b2; pf1u.u[3] = b3;        \
    }                                                                          \
    {                                                                          \
        _Pragma("unroll")                                                      \
        for (int db = 0; db < 4; ++db) {                                       \
            const int vrow = db * 32 + l32;                                    \
            const int swv = vrow & 7;                                          \
            const char* vp = (BUF) + XBT_REL + vrow * 256;                     \
            bf16x8 v0 = *(const bf16x8*)(vp + (((4 * kh + h5) ^ swv) * 16));   \
            oacc[db] = __builtin_amdgcn_mfma_f32_32x32x16_bf16(                \
                pf0u.v, v0, oacc[db], 0, 0, 0);                                \
            bf16x8 v1 = *(const bf16x8*)(vp + (((4 * kh + 2 + h5) ^ swv) * 16)); \
            oacc[db] = __builtin_amdgcn_mfma_f32_32x32x16_bf16(                \
                pf1u.v, v1, oacc[db], 0, 0, 0);                                \
        }                                                                      \
    }                                                                          \
} while (0)

    // ---- pipelined main loop: one barrier/tile; adj 2 ahead; stage 1 ahead
    for (int kt = 0; kt < NT - 1; ++kt) {
        // steady queue here: [adj(kt) 4, stage(kt) 8, adj(kt+1) 4]
        asm volatile("s_waitcnt vmcnt(4)" ::: "memory");  // drain adj(kt)+stage(kt)
        __builtin_amdgcn_s_barrier();
        STAGE(bufB, (kt + 1) * BK);                       // under COMPUTE(kt)
        if (kt + 2 < NT) {
            #pragma unroll
            for (int g = 0; g < 4; ++g)
                avC[g] = *(const int4*)(arow + (kt + 2) * BK + g * 8);
        }
        COMPUTE(bufA, avA);
        char* tmp = bufA; bufA = bufB; bufB = tmp;
        #pragma unroll
        for (int g = 0; g < 4; ++g) { avA[g] = avB[g]; avB[g] = avC[g]; }
    }
    asm volatile("s_waitcnt vmcnt(0)" ::: "memory");
    __builtin_amdgcn_s_barrier();
    COMPUTE(bufA, avA);

    // ---------------- epilogue: combine 4 key-quarters, normalize, store
    psum += __shfl_xor(psum, 32, 64);      // fold h5 halves (same q)
    __syncthreads();                        // all tiles done; repurpose LDS

    // slot w: [32 q][136 f32 stride] partial O
    float* slot = (float*)(lds + w * 17408);
    #pragma unroll
    for (int db = 0; db < 4; ++db)
        #pragma unroll
        for (int r = 0; r < 16; ++r) {
            const int lrow = (r & 3) + 8 * (r >> 2) + 4 * h5;
            slot[lrow * 136 + db * 32 + l32] = oacc[db][r];
        }
    float* psarea = (float*)(lds + PS_OFF);  // [8 waves][32 q]
    if (l < 32) psarea[w * 32 + l] = psum;
    __syncthreads();

    {
        const int R   = w * 8 + (l >> 3);    // block-local out row 0..63
        const int q32 = R & 31, rwR = R >> 5;
        const int d0  = (l & 7) * 16;
        float tot = psarea[(rwR * 4 + 0) * 32 + q32]
                  + psarea[(rwR * 4 + 1) * 32 + q32]
                  + psarea[(rwR * 4 + 2) * 32 + q32]
                  + psarea[(rwR * 4 + 3) * 32 + q32];
        float invt = 1.0f / tot;
        float4 acc[4];
        #pragma unroll
        for (int j = 0; j < 4; ++j) acc[j] = (float4){0.f, 0.f, 0.f, 0.f};
        #pragma unroll
        for (int kx = 0; kx < 4; ++kx) {
            const float* sp = (const float*)(lds + (rwR * 4 + kx) * 17408)
                              + q32 * 136 + d0;
            #pragma unroll
            for (int j = 0; j < 4; ++j) {
                float4 v = *(const float4*)(sp + 4 * j);
                acc[j].x += v.x; acc[j].y += v.y;
                acc[j].z += v.z; acc[j].w += v.w;
            }
        }
        float* op = Og + (size_t)(row0 + R) * DD + d0;
        #pragma unroll
        for (int j = 0; j < 4; ++j) {
            float4 res;
            res.x = acc[j].x * invt; res.y = acc[j].y * invt;
            res.z = acc[j].z * invt; res.w = acc[j].w * invt;
            *(float4*)(op + 4 * j) = res;
        }
    }
#undef COMPUTE
#undef STAGE
}

extern "C" void kernel_launch(void* const* d_in, const int* in_sizes, int n_in,
                              void* d_out, int out_size, void* d_ws, size_t ws_size,
                              hipStream_t stream) {
    const float* X   = (const float*)d_in[0];
    const int*   adj = (const int*)d_in[1];
    float*       out = (float*)d_out;
    unsigned short* xb  = (unsigned short*)d_ws;              // 4 MB bf16 X
    unsigned short* xbt = xb + (size_t)4 * NN * DD;           // 4 MB bf16 X^T

    hipFuncSetAttribute((const void*)gat_fused,
                        hipFuncAttributeMaxDynamicSharedMemorySize, LDS_BYTES);
    gat_prep<<<dim3(256), dim3(256), 0, stream>>>(X, xb, xbt);
    gat_fused<<<dim3(256), dim3(512), LDS_BYTES, stream>>>(xb, xbt, adj, out);
}

// Round 11
// 376.863 us; speedup vs baseline: 1.1022x; 1.0485x over previous
//
#include <hip/hip_runtime.h>
#include <hip/hip_bf16.h>

// GAT fused masked attention, B=4 N=4096 D=128 fp32.
// Round 9 kernel, 3rd submit (broker timeouts; never ran).
// Kill the hidden vmcnt(0): unroll-2 K-loop with NAMED adj reg sets
// (avE/avO) -> no register rotation of in-flight loads -> compiler waits
// become vmcnt(12) no-ops; explicit vmcnt(4) is the only real sync.
// Riders: XOR swizzle mask &7->&15 (4-way -> 2-way LDS conflicts, free),
// batch-grouped bid remap (per-XCD L2 tile reuse 256KB->64KB per tile).
// Structure: 8 waves (2 q-halves x 4 key-quarters), 32x32x16 MFMA, T12
// in-register P via cvt_pk+permlane32_swap. Needs ws_size >= 8 MB.

#define NN 4096
#define DD 128
#define BK 128
#define NT (NN / BK)

#define XBT_REL 32768                    // xbt tile within a buffer
#define BUF1_OFF 65536
#define PS_OFF 139264                    // psarea after epilogue slots
#define LDS_BYTES (PS_OFF + 1024)        // 140288

typedef __attribute__((ext_vector_type(8))) short bf16x8;
typedef __attribute__((ext_vector_type(16))) float f32x16;

static __device__ __forceinline__ unsigned f2bf(float f) {
    union { float f; unsigned u; } v; v.f = f;
    return (v.u + 0x7fffu + ((v.u >> 16) & 1u)) >> 16;  // RNE
}

static __device__ __forceinline__ void gl_lds16(const void* g, void* l) {
    __builtin_amdgcn_global_load_lds(
        (const __attribute__((address_space(1))) unsigned*)g,
        (__attribute__((address_space(3))) unsigned*)l, 16, 0, 0);
}

static __device__ __forceinline__ unsigned cvtpk(float lo, float hi) {
    unsigned r;
    asm("v_cvt_pk_bf16_f32 %0, %1, %2" : "=v"(r) : "v"(lo), "v"(hi));
    return r;
}
// swap: a' = (a_lo, b_lo), b' = (a_hi, b_hi) across the lane<32 / lane>=32 halves
static __device__ __forceinline__ void plswap(unsigned& a, unsigned& b) {
    asm volatile("v_permlane32_swap_b32 %0, %1" : "+v"(a), "+v"(b));
}

// ---------------- prepass: X fp32 -> xb (bf16 [b][n][d]) + xbt (bf16 [b][d][n])
__global__ __launch_bounds__(256)
void gat_prep(const float* __restrict__ X, unsigned short* __restrict__ xb,
              unsigned short* __restrict__ xbt) {
    __shared__ unsigned short tile[64][132];
    const int t = threadIdx.x;
    const int b  = blockIdx.x >> 6;
    const int kc = blockIdx.x & 63;
    const float* src = X + ((size_t)b * NN + kc * 64) * DD;
    unsigned short* xbo = xb + ((size_t)b * NN + kc * 64) * DD;

    #pragma unroll
    for (int it = 0; it < 8; ++it) {
        int f = it * 256 + t;
        int k = f >> 5, d4 = (f & 31) * 4;
        float4 v = *(const float4*)(src + (size_t)f * 4);
        uint2 pk;
        pk.x = f2bf(v.x) | (f2bf(v.y) << 16);
        pk.y = f2bf(v.z) | (f2bf(v.w) << 16);
        *(uint2*)(xbo + (size_t)f * 4) = pk;
        *(uint2*)(&tile[k][d4]) = pk;
    }
    __syncthreads();
    const int d = t >> 1, kb0 = (t & 1) * 32;
    unsigned short* dst = xbt + (size_t)b * DD * NN + (size_t)d * NN + kc * 64 + kb0;
    #pragma unroll
    for (int c = 0; c < 4; ++c) {
        union { uint4 o; unsigned short e[8]; } u;
        #pragma unroll
        for (int j = 0; j < 8; ++j) u.e[j] = tile[kb0 + c * 8 + j][d];
        *(uint4*)(dst + c * 8) = u.o;
    }
}

// ---------------- main fused kernel: 512 thr = 8 waves (rw 2 x kh 4)
__global__ __launch_bounds__(512, 2)
void gat_fused(const unsigned short* __restrict__ xb,
               const unsigned short* __restrict__ xbt,
               const int* __restrict__ adj,
               float* __restrict__ out) {
    extern __shared__ char lds[];
    const int t = threadIdx.x;
    const int w = t >> 6, l = t & 63;
    const int l32 = l & 31, h5 = l >> 5;
    const int rw = w >> 2;         // 0..1: 32 q rows each
    const int kh = w & 3;          // 0..3: 32 keys each

    // batch-grouped remap: XCD pair {2k,2k+1} serves batch k (L2 tile reuse)
    const int bid0 = blockIdx.x;
    const int bid  = ((bid0 & 7) >> 1) * 64 + (bid0 & 1) * 32 + (bid0 >> 3);
    const int b    = bid >> 6;
    const int row0 = (bid & 63) * 64;
    const int qbase = row0 + rw * 32;
    const int kbase = kh * 32;

    const char* xb_b  = (const char*)(xb  + (size_t)b * NN * DD);
    const char* xbt_b = (const char*)(xbt + (size_t)b * DD * NN);
    const int*  Ag    = adj + (size_t)b * NN * NN;
    float*      Og    = out + (size_t)b * NN * DD;

    // Q as B-operand frags (row q = l32, k-chunks of 16): 8 x bf16x8 in regs
    bf16x8 qfrag[8];
    {
        const char* qp = xb_b + (size_t)(qbase + l32) * 256;
        #pragma unroll
        for (int c = 0; c < 8; ++c)
            qfrag[c] = *(const bf16x8*)(qp + c * 32 + h5 * 16);
    }

    // staging: 4 xb + 4 xbt gl_lds16 per wave; src XOR-swizzled (&15), LDS linear
    int off_xb[4], off_xbt[4];
    #pragma unroll
    for (int j = 0; j < 4; ++j) {
        int r = w * 16 + 4 * j + (l >> 4);
        off_xb[j]  = r * 256      + (((l & 15) ^ (r & 15)) * 16);
        off_xbt[j] = r * (NN * 2) + (((l & 15) ^ (r & 15)) * 16);
    }
    char* bufA = lds;
    char* bufB = lds + BUF1_OFF;
    const int* arow = Ag + (size_t)(qbase + l32) * NN + kbase + 4 * h5;

#define STAGE(BUF, KEY0) do {                                                  \
    _Pragma("unroll")                                                          \
    for (int j = 0; j < 4; ++j) {                                              \
        gl_lds16(xb_b  + (size_t)(KEY0) * 256 + off_xb[j],                     \
                 (BUF) + w * 4096 + j * 1024);                                 \
        gl_lds16(xbt_b + (size_t)(KEY0) * 2 + off_xbt[j],                      \
                 (BUF) + XBT_REL + w * 4096 + j * 1024);                       \
    }                                                                          \
} while (0)

#define LOAD_ADJ(AV, KT) do {                                                  \
    _Pragma("unroll")                                                          \
    for (int g = 0; g < 4; ++g)                                                \
        (AV)[g] = *(const int4*)(arow + (size_t)(KT) * BK + g * 8);            \
} while (0)

    f32x16 oacc[4];
    #pragma unroll
    for (int d = 0; d < 4; ++d) oacc[d] = (f32x16)(0.0f);
    float psum = 0.f;

#define COMPUTE(BUF, AV) do {                                                  \
    f32x16 sacc = (f32x16)(0.0f);                                              \
    {                                                                          \
        const int krow = kbase + l32;                                          \
        const char* kp = (BUF) + krow * 256;                                   \
        const int sw = krow & 15;                                              \
        _Pragma("unroll")                                                      \
        for (int c = 0; c < 8; ++c) {                                          \
            bf16x8 kf = *(const bf16x8*)(kp + (((2 * c + h5) ^ sw) * 16));     \
            sacc = __builtin_amdgcn_mfma_f32_32x32x16_bf16(                    \
                kf, qfrag[c], sacc, 0, 0, 0);                                  \
        }                                                                      \
    }                                                                          \
    float p[16];                                                               \
    {                                                                          \
        const float SC = 0.08838834764831845f;  /* 1/sqrt(128) */              \
        _Pragma("unroll")                                                      \
        for (int g = 0; g < 4; ++g) {                                          \
            int4 a = (AV)[g];                                                  \
            p[4*g+0] = (a.x > 0) ? __expf(sacc[4*g+0] * SC) : 0.f;             \
            p[4*g+1] = (a.y > 0) ? __expf(sacc[4*g+1] * SC) : 0.f;             \
            p[4*g+2] = (a.z > 0) ? __expf(sacc[4*g+2] * SC) : 0.f;             \
            p[4*g+3] = (a.w > 0) ? __expf(sacc[4*g+3] * SC) : 0.f;             \
            psum += p[4*g+0] + p[4*g+1] + p[4*g+2] + p[4*g+3];                 \
        }                                                                      \
    }                                                                          \
    /* T12: assemble PV A-frags in-register (lane q=l32 holds 32 keys). */     \
    union { bf16x8 v; unsigned u[4]; } pf0u, pf1u;                             \
    {                                                                          \
        unsigned a0 = cvtpk(p[0],  p[1]),  b0 = cvtpk(p[4],  p[5]);            \
        unsigned a1 = cvtpk(p[2],  p[3]),  b1 = cvtpk(p[6],  p[7]);            \
        plswap(a0, b0);  plswap(a1, b1);                                       \
        pf0u.u[0] = a0; pf0u.u[1] = a1; pf0u.u[2] = b0; pf0u.u[3] = b1;        \
        unsigned a2 = cvtpk(p[8],  p[9]),  b2 = cvtpk(p[12], p[13]);           \
        unsigned a3 = cvtpk(p[10], p[11]), b3 = cvtpk(p[14], p[15]);           \
        plswap(a2, b2);  plswap(a3, b3);                                       \
        pf1u.u[0] = a2; pf1u.u[1] = a3; pf1u.u[2] = b2; pf1u.u[3] = b3;        \
    }                                                                          \
    {                                                                          \
        _Pragma("unroll")                                                      \
        for (int db = 0; db < 4; ++db) {                                       \
            const int vrow = db * 32 + l32;                                    \
            const int swv = vrow & 15;                                         \
            const char* vp = (BUF) + XBT_REL + vrow * 256;                     \
            bf16x8 v0 = *(const bf16x8*)(vp + (((4 * kh + h5) ^ swv) * 16));   \
            oacc[db] = __builtin_amdgcn_mfma_f32_32x32x16_bf16(                \
                pf0u.v, v0, oacc[db], 0, 0, 0);                                \
            bf16x8 v1 = *(const bf16x8*)(vp + (((4 * kh + 2 + h5) ^ swv) * 16)); \
            oacc[db] = __builtin_amdgcn_mfma_f32_32x32x16_bf16(                \
                pf1u.v, v1, oacc[db], 0, 0, 0);                                \
        }                                                                      \
    }                                                                          \
} while (0)

    // ---- prologue: stage tile 0, adj tile 0 ----
    STAGE(bufA, 0);
    int4 avE[4], avO[4];
    LOAD_ADJ(avE, 0);

    // ---- unroll-2 pipelined loop: no reg rotation => no hidden vmcnt(0) ----
    // steady queue at each wait: [avCur 4, stage(kt) 8, avNext 4] -> vmcnt(4)
    for (int kt = 0; kt < NT - 2; kt += 2) {
        LOAD_ADJ(avO, kt + 1);
        asm volatile("s_waitcnt vmcnt(4)" ::: "memory");
        __builtin_amdgcn_s_barrier();
        STAGE(bufB, (kt + 1) * BK);
        COMPUTE(bufA, avE);

        LOAD_ADJ(avE, kt + 2);
        asm volatile("s_waitcnt vmcnt(4)" ::: "memory");
        __builtin_amdgcn_s_barrier();
        STAGE(bufA, (kt + 2) * BK);
        COMPUTE(bufB, avO);
    }
    // ---- tail: tiles NT-2, NT-1 ----
    LOAD_ADJ(avO, NT - 1);
    asm volatile("s_waitcnt vmcnt(4)" ::: "memory");
    __builtin_amdgcn_s_barrier();
    STAGE(bufB, (NT - 1) * BK);
    COMPUTE(bufA, avE);

    asm volatile("s_waitcnt vmcnt(0)" ::: "memory");
    __builtin_amdgcn_s_barrier();
    COMPUTE(bufB, avO);

    // ---------------- epilogue: combine 4 key-quarters, normalize, store
    psum += __shfl_xor(psum, 32, 64);      // fold h5 halves (same q)
    __syncthreads();                        // all tiles done; repurpose LDS

    // slot w: [32 q][136 f32 stride] partial O
    float* slot = (float*)(lds + w * 17408);
    #pragma unroll
    for (int db = 0; db < 4; ++db)
        #pragma unroll
        for (int r = 0; r < 16; ++r) {
            const int lrow = (r & 3) + 8 * (r >> 2) + 4 * h5;
            slot[lrow * 136 + db * 32 + l32] = oacc[db][r];
        }
    float* psarea = (float*)(lds + PS_OFF);  // [8 waves][32 q]
    if (l < 32) psarea[w * 32 + l] = psum;
    __syncthreads();

    {
        const int R   = w * 8 + (l >> 3);    // block-local out row 0..63
        const int q32 = R & 31, rwR = R >> 5;
        const int d0  = (l & 7) * 16;
        float tot = psarea[(rwR * 4 + 0) * 32 + q32]
                  + psarea[(rwR * 4 + 1) * 32 + q32]
                  + psarea[(rwR * 4 + 2) * 32 + q32]
                  + psarea[(rwR * 4 + 3) * 32 + q32];
        float invt = 1.0f / tot;
        float4 acc[4];
        #pragma unroll
        for (int j = 0; j < 4; ++j) acc[j] = (float4){0.f, 0.f, 0.f, 0.f};
        #pragma unroll
        for (int kx = 0; kx < 4; ++kx) {
            const float* sp = (const float*)(lds + (rwR * 4 + kx) * 17408)
                              + q32 * 136 + d0;
            #pragma unroll
            for (int j = 0; j < 4; ++j) {
                float4 v = *(const float4*)(sp + 4 * j);
                acc[j].x += v.x; acc[j].y += v.y;
                acc[j].z += v.z; acc[j].w += v.w;
            }
        }
        float* op = Og + (size_t)(row0 + R) * DD + d0;
        #pragma unroll
        for (int j = 0; j < 4; ++j) {
            float4 res;
            res.x = acc[j].x * invt; res.y = acc[j].y * invt;
            res.z = acc[j].z * invt; res.w = acc[j].w * invt;
            *(float4*)(op + 4 * j) = res;
        }
    }
#undef COMPUTE
#undef STAGE
#undef LOAD_ADJ
}

extern "C" void kernel_launch(void* const* d_in, const int* in_sizes, int n_in,
                              void* d_out, int out_size, void* d_ws, size_t ws_size,
                              hipStream_t stream) {
    const float* X   = (const float*)d_in[0];
    const int*   adj = (const int*)d_in[1];
    float*       out = (float*)d_out;
    unsigned short* xb  = (unsigned short*)d_ws;              // 4 MB bf16 X
    unsigned short* xbt = xb + (size_t)4 * NN * DD;           // 4 MB bf16 X^T

    hipFuncSetAttribute((const void*)gat_fused,
                        hipFuncAttributeMaxDynamicSharedMemorySize, LDS_BYTES);
    gat_prep<<<dim3(256), dim3(256), 0, stream>>>(X, xb, xbt);
    gat_fused<<<dim3(256), dim3(512), LDS_BYTES, stream>>>(xb, xbt, adj, out);
}